// Round 2
// baseline (194.946 us; speedup 1.0000x reference)
//
#include <hip/hip_runtime.h>

// GAE: (B=8192, T=256, A=4, 1) fp32.
// g[t] = d[t] + c[t]*g[t+1], c = GAMMA*LMBDA*(1-term), g[T]=0
// adv = g, ret = g + v. d_out = [adv | ret] flat.
//
// Structure: coalesced float4 I/O (thread=timestep) + 16-chunk wave scan
// (thread=(tc,a)) bridged by an LDS transpose. One wave per sequence.
//
// Round-5 changes (latency theory, from VGPR_Count=32 @ 2.4TB/s / 30% peak):
//  - __launch_bounds__(256,4): 128-VGPR budget so all 16 float4 loads of a
//    sequence can be in flight at once (r1's 32-VGPR alloc serialized them).
//  - 2 sequences per wave, software-pipelined: seq-1 loads issued while
//    seq-0 scans/stores -> high load-in-flight duty cycle.
//  - No __syncthreads: LDS slices are wave-private; wave-local
//    s_waitcnt lgkmcnt(0) orders the transpose phases without draining the
//    prefetch's vmcnt across waves.
//  - Non-temporal float4 stores: outputs are never re-read; keep the 134MB
//    of inputs L3-resident instead of evicting them.
//
// LDS scan layout: 16 rows (j = s%16) x 64 cols, col swizzled by 4*row so
// both access phases are <=2-way bank aliased (free on gfx950).
// Continuation flag stored as byte (c ∈ {0, GAMMA*LMBDA}); LDS = 20KB/block.

#define GAMMA 0.99f
#define LMBDA 0.95f

typedef float f32x4 __attribute__((ext_vector_type(4)));
typedef unsigned char u8;

constexpr float K0 = GAMMA * LMBDA;

__device__ __forceinline__ void issue_loads(
    const f32x4* __restrict__ R4, const f32x4* __restrict__ T4,
    const f32x4* __restrict__ V4, const f32x4* __restrict__ N4,
    int b, int lane, f32x4 r[4], f32x4 tm[4], f32x4 v[4], f32x4 nv[4])
{
#pragma unroll
    for (int q = 0; q < 4; ++q) {
        const int gi = b * 256 + 64 * q + lane;
        r[q]  = R4[gi];
        tm[q] = T4[gi];
        v[q]  = V4[gi];
        nv[q] = N4[gi];
    }
}

// Consume loaded regs: compute (d, cont-flag), transpose-write into LDS.
__device__ __forceinline__ void phaseA(
    float* __restrict__ D_, u8* __restrict__ C_, int lane,
    const f32x4 r[4], const f32x4 tm[4], const f32x4 nv[4], const f32x4 v[4])
{
#pragma unroll
    for (int q = 0; q < 4; ++q) {
        const int f    = 64 * q + lane;          // float4 index = timestep t
        const int s    = 255 - f;                // scan index (reversed time)
        const int row  = s & 15;
        const int col  = (4 * (s >> 4) + 4 * row) & 63;
        const int addr = row * 64 + col;         // 4-aligned

        f32x4 d4;
        d4.x = r[q].x + GAMMA * nv[q].x * (1.0f - tm[q].x) - v[q].x;
        d4.y = r[q].y + GAMMA * nv[q].y * (1.0f - tm[q].y) - v[q].y;
        d4.z = r[q].z + GAMMA * nv[q].z * (1.0f - tm[q].z) - v[q].z;
        d4.w = r[q].w + GAMMA * nv[q].w * (1.0f - tm[q].w) - v[q].w;
        const unsigned pk = (tm[q].x == 0.0f ? 0x00000001u : 0u)
                          | (tm[q].y == 0.0f ? 0x00000100u : 0u)
                          | (tm[q].z == 0.0f ? 0x00010000u : 0u)
                          | (tm[q].w == 0.0f ? 0x01000000u : 0u);
        *((f32x4*)&D_[addr])    = d4;
        *((unsigned*)&C_[addr]) = pk;
    }
}

// Wave scan over LDS slice + transposed coalesced non-temporal stores.
__device__ __forceinline__ void scan_store(
    float* __restrict__ D_, const u8* __restrict__ C_,
    int lane, int b, const f32x4 v4[4],
    f32x4* __restrict__ adv4, f32x4* __restrict__ ret4)
{
    // Wave-local ordering: phase-A ds_writes complete before phase-B ds_reads.
    asm volatile("s_waitcnt lgkmcnt(0)" ::: "memory");

    const int tc = lane >> 2;    // time chunk 0..15
    const int a  = lane & 3;     // agent channel

    float d[16];
    unsigned mask = 0;           // bit j = continuation flag of step j
#pragma unroll
    for (int j = 0; j < 16; ++j) {
        const int col = (4 * tc + 4 * j + a) & 63;
        d[j] = D_[j * 64 + col];
        mask |= ((unsigned)C_[j * 64 + col]) << j;
    }

    // Local chunk composite: out = D + K * in.
    float D = d[0];
    float K = (mask & 1u) ? K0 : 0.0f;
#pragma unroll
    for (int j = 1; j < 16; ++j) {
        const float cj = ((mask >> j) & 1u) ? K0 : 0.0f;
        D = d[j] + cj * D;
        K = cj * K;
    }

    // Inclusive shuffle scan over tc (lane stride 4): 4 steps.
#pragma unroll
    for (int s2 = 1; s2 < 16; s2 <<= 1) {
        const float pD = __shfl_up(D, (unsigned)(4 * s2), 64);
        const float pK = __shfl_up(K, (unsigned)(4 * s2), 64);
        if (tc >= s2) { D = D + K * pD; K = K * pK; }
    }

    // Exclusive prefix = state entering this chunk.
    float x = __shfl_up(D, 4u, 64);
    if (tc == 0) x = 0.0f;

    // Replay chunk, write g back into D-buffer (d already in regs).
    float g = x;
#pragma unroll
    for (int j = 0; j < 16; ++j) {
        const float cj = ((mask >> j) & 1u) ? K0 : 0.0f;
        g = d[j] + cj * g;
        const int col = (4 * tc + 4 * j + a) & 63;
        D_[j * 64 + col] = g;
    }
    asm volatile("s_waitcnt lgkmcnt(0)" ::: "memory");

    // Transpose-read g, coalesced non-temporal float4 stores.
#pragma unroll
    for (int q = 0; q < 4; ++q) {
        const int f   = 64 * q + lane;
        const int s   = 255 - f;
        const int row = s & 15;
        const int col = (4 * (s >> 4) + 4 * row) & 63;
        const f32x4 g4 = *((const f32x4*)&D_[row * 64 + col]);

        const int gi = b * 256 + f;
        __builtin_nontemporal_store(g4, &adv4[gi]);
        const f32x4 rt = g4 + v4[q];
        __builtin_nontemporal_store(rt, &ret4[gi]);
    }
    // Keep the following phase-A ds_writes after this phase's ds_reads.
    asm volatile("" ::: "memory");
}

__global__ __launch_bounds__(256, 4) void gae_scan_kernel(
    const float* __restrict__ reward,
    const float* __restrict__ terminated,
    const float* __restrict__ value,
    const float* __restrict__ next_value,
    float* __restrict__ adv_out,
    float* __restrict__ ret_out)
{
    __shared__ float bufD[4][16 * 64];           // 16 KB: d, then reused for g
    __shared__ u8    bufC[4][16 * 64];           //  4 KB: continuation flags

    const int w    = threadIdx.x >> 6;
    const int lane = threadIdx.x & 63;
    const int wid  = blockIdx.x * 4 + w;

    float* __restrict__ D_ = bufD[w];
    u8*    __restrict__ C_ = bufC[w];

    const f32x4* R4 = (const f32x4*)reward;
    const f32x4* T4 = (const f32x4*)terminated;
    const f32x4* V4 = (const f32x4*)value;
    const f32x4* N4 = (const f32x4*)next_value;
    f32x4* adv4 = (f32x4*)adv_out;
    f32x4* ret4 = (f32x4*)ret_out;

    const int b0 = wid;          // first sequence
    const int b1 = wid + 4096;   // second sequence (pipelined)

    f32x4 r0[4], t0[4], v0[4], n0[4];
    issue_loads(R4, T4, V4, N4, b0, lane, r0, t0, v0, n0);
    phaseA(D_, C_, lane, r0, t0, n0, v0);

    f32x4 r1[4], t1[4], v1[4], n1[4];
    issue_loads(R4, T4, V4, N4, b1, lane, r1, t1, v1, n1);  // prefetch

    scan_store(D_, C_, lane, b0, v0, adv4, ret4);

    phaseA(D_, C_, lane, r1, t1, n1, v1);
    scan_store(D_, C_, lane, b1, v1, adv4, ret4);
}

extern "C" void kernel_launch(void* const* d_in, const int* in_sizes, int n_in,
                              void* d_out, int out_size, void* d_ws, size_t ws_size,
                              hipStream_t stream) {
    const float* reward     = (const float*)d_in[0];
    const float* terminated = (const float*)d_in[1];
    const float* value      = (const float*)d_in[2];
    const float* next_value = (const float*)d_in[3];

    const int B = 8192;
    const int n_elem = B * 256 * 4;          // 8388608
    float* adv = (float*)d_out;
    float* ret = adv + n_elem;

    // 8 sequences per block (4 waves x 2 pipelined) -> 1024 blocks.
    gae_scan_kernel<<<B / 8, 256, 0, stream>>>(reward, terminated, value,
                                               next_value, adv, ret);
}

// Round 3
// 176.451 us; speedup vs baseline: 1.1048x; 1.1048x over previous
//
#include <hip/hip_runtime.h>

// GAE: (B=8192, T=256, A=4, 1) fp32.
// g[t] = d[t] + c[t]*g[t+1], c = GAMMA*LMBDA*(1-term), g[T]=0
// adv = g, ret = g + v. d_out = [adv | ret] flat.
//
// Round-6 structure (DRAM-locality theory):
//   r0-r2 all plateaued at 2.4 TB/s (30% peak) regardless of occupancy/MLP
//   structure. Diagnosis: one-shot grids make ALL blocks co-resident, each
//   streaming private 4-16KB windows scattered over the full 134MB ->
//   ~10-30K concurrent DRAM streams -> row-buffer thrash -> ~30% BW and
//   queue-inflated latency (waves measured ~92K cyc/seq). r2 spreading its
//   2nd sequence +64MB away made it WORSE (85us, FETCH up) - consistent.
//
//   Fix: persistent compact front. 512 blocks (2/CU, 8 waves/CU), 2048
//   waves; wave w handles seqs g*2048+w, g=0..3. At any instant the device
//   reads a ~8MB contiguous sliding window per array (copy-kernel-like).
//   2-deep register prefetch of seq g+1 overlaps the scan of seq g
//   (launch_bounds(256,2) -> 256-VGPR budget, no sandbagging excuse).
//   NT stores reverted (r2: WRITE_SIZE 96->113MB, worse).
//
// Per-wave phases (verified since r1):
//   A: coalesced float4 loads (thread=timestep), compute (d, cont-flag),
//      transpose-write into wave-private LDS slice (swizzled, <=2-way).
//   B: thread (tc,a) owns 16 steps; chunk composite + 4-round shuffle scan
//      + replay. Wave-local s_waitcnt lgkmcnt(0) instead of __syncthreads.
//   C: transpose-read g, coalesced float4 stores of adv and ret=g+v.

#define GAMMA 0.99f
#define LMBDA 0.95f

typedef float f32x4 __attribute__((ext_vector_type(4)));
typedef unsigned char u8;

constexpr float K0 = GAMMA * LMBDA;

__device__ __forceinline__ void issue_loads(
    const f32x4* __restrict__ R4, const f32x4* __restrict__ T4,
    const f32x4* __restrict__ V4, const f32x4* __restrict__ N4,
    int b, int lane, f32x4 r[4], f32x4 tm[4], f32x4 v[4], f32x4 nv[4])
{
#pragma unroll
    for (int q = 0; q < 4; ++q) {
        const int gi = b * 256 + 64 * q + lane;
        r[q]  = R4[gi];
        tm[q] = T4[gi];
        v[q]  = V4[gi];
        nv[q] = N4[gi];
    }
}

// Consume loaded regs: compute (d, cont-flag), transpose-write into LDS.
__device__ __forceinline__ void phaseA(
    float* __restrict__ D_, u8* __restrict__ C_, int lane,
    const f32x4 r[4], const f32x4 tm[4], const f32x4 nv[4], const f32x4 v[4])
{
#pragma unroll
    for (int q = 0; q < 4; ++q) {
        const int f    = 64 * q + lane;          // float4 index = timestep t
        const int s    = 255 - f;                // scan index (reversed time)
        const int row  = s & 15;
        const int col  = (4 * (s >> 4) + 4 * row) & 63;
        const int addr = row * 64 + col;         // 4-aligned

        f32x4 d4;
        d4.x = r[q].x + GAMMA * nv[q].x * (1.0f - tm[q].x) - v[q].x;
        d4.y = r[q].y + GAMMA * nv[q].y * (1.0f - tm[q].y) - v[q].y;
        d4.z = r[q].z + GAMMA * nv[q].z * (1.0f - tm[q].z) - v[q].z;
        d4.w = r[q].w + GAMMA * nv[q].w * (1.0f - tm[q].w) - v[q].w;
        const unsigned pk = (tm[q].x == 0.0f ? 0x00000001u : 0u)
                          | (tm[q].y == 0.0f ? 0x00000100u : 0u)
                          | (tm[q].z == 0.0f ? 0x00010000u : 0u)
                          | (tm[q].w == 0.0f ? 0x01000000u : 0u);
        *((f32x4*)&D_[addr])    = d4;
        *((unsigned*)&C_[addr]) = pk;
    }
}

// Wave scan over LDS slice + transposed coalesced stores.
__device__ __forceinline__ void scan_store(
    float* __restrict__ D_, const u8* __restrict__ C_,
    int lane, int b, const f32x4 v4[4],
    f32x4* __restrict__ adv4, f32x4* __restrict__ ret4)
{
    // Wave-local ordering: phase-A ds_writes complete before phase-B ds_reads.
    asm volatile("s_waitcnt lgkmcnt(0)" ::: "memory");

    const int tc = lane >> 2;    // time chunk 0..15
    const int a  = lane & 3;     // agent channel

    float d[16];
    unsigned mask = 0;           // bit j = continuation flag of step j
#pragma unroll
    for (int j = 0; j < 16; ++j) {
        const int col = (4 * tc + 4 * j + a) & 63;
        d[j] = D_[j * 64 + col];
        mask |= ((unsigned)C_[j * 64 + col]) << j;
    }

    // Local chunk composite: out = D + K * in.
    float D = d[0];
    float K = (mask & 1u) ? K0 : 0.0f;
#pragma unroll
    for (int j = 1; j < 16; ++j) {
        const float cj = ((mask >> j) & 1u) ? K0 : 0.0f;
        D = d[j] + cj * D;
        K = cj * K;
    }

    // Inclusive shuffle scan over tc (lane stride 4): 4 steps.
#pragma unroll
    for (int s2 = 1; s2 < 16; s2 <<= 1) {
        const float pD = __shfl_up(D, (unsigned)(4 * s2), 64);
        const float pK = __shfl_up(K, (unsigned)(4 * s2), 64);
        if (tc >= s2) { D = D + K * pD; K = K * pK; }
    }

    // Exclusive prefix = state entering this chunk.
    float x = __shfl_up(D, 4u, 64);
    if (tc == 0) x = 0.0f;

    // Replay chunk, write g back into D-buffer (d already in regs).
    float g = x;
#pragma unroll
    for (int j = 0; j < 16; ++j) {
        const float cj = ((mask >> j) & 1u) ? K0 : 0.0f;
        g = d[j] + cj * g;
        const int col = (4 * tc + 4 * j + a) & 63;
        D_[j * 64 + col] = g;
    }
    asm volatile("s_waitcnt lgkmcnt(0)" ::: "memory");

    // Transpose-read g, coalesced float4 stores.
#pragma unroll
    for (int q = 0; q < 4; ++q) {
        const int f   = 64 * q + lane;
        const int s   = 255 - f;
        const int row = s & 15;
        const int col = (4 * (s >> 4) + 4 * row) & 63;
        const f32x4 g4 = *((const f32x4*)&D_[row * 64 + col]);

        const int gi = b * 256 + f;
        adv4[gi] = g4;
        ret4[gi] = g4 + v4[q];
    }
    // Keep the following phase-A ds_writes ordered after this phase's reads.
    asm volatile("" ::: "memory");
}

__global__ __launch_bounds__(256, 2) void gae_scan_kernel(
    const float* __restrict__ reward,
    const float* __restrict__ terminated,
    const float* __restrict__ value,
    const float* __restrict__ next_value,
    float* __restrict__ adv_out,
    float* __restrict__ ret_out)
{
    __shared__ float bufD[4][16 * 64];           // 16 KB: d, then reused for g
    __shared__ u8    bufC[4][16 * 64];           //  4 KB: continuation flags

    const int w    = threadIdx.x >> 6;
    const int lane = threadIdx.x & 63;
    const int wv   = blockIdx.x * 4 + w;         // global wave id, 0..2047

    float* __restrict__ D_ = bufD[w];
    u8*    __restrict__ C_ = bufC[w];

    const f32x4* R4 = (const f32x4*)reward;
    const f32x4* T4 = (const f32x4*)terminated;
    const f32x4* V4 = (const f32x4*)value;
    const f32x4* N4 = (const f32x4*)next_value;
    f32x4* adv4 = (f32x4*)adv_out;
    f32x4* ret4 = (f32x4*)ret_out;

    // Double-buffered register sets for the 2-deep prefetch pipeline.
    f32x4 r[2][4], tm[2][4], v[2][4], nv[2][4];

    issue_loads(R4, T4, V4, N4, wv, lane, r[0], tm[0], v[0], nv[0]);

#pragma unroll
    for (int g = 0; g < 4; ++g) {
        const int cb = g & 1;        // unrolled -> compile-time constant
        const int nb = cb ^ 1;
        const int b  = g * 2048 + wv;

        phaseA(D_, C_, lane, r[cb], tm[cb], nv[cb], v[cb]);

        if (g < 3) {
            // Prefetch next sequence; in flight during the scan below.
            issue_loads(R4, T4, V4, N4, b + 2048, lane,
                        r[nb], tm[nb], v[nb], nv[nb]);
        }

        scan_store(D_, C_, lane, b, v[cb], adv4, ret4);
    }
}

extern "C" void kernel_launch(void* const* d_in, const int* in_sizes, int n_in,
                              void* d_out, int out_size, void* d_ws, size_t ws_size,
                              hipStream_t stream) {
    const float* reward     = (const float*)d_in[0];
    const float* terminated = (const float*)d_in[1];
    const float* value      = (const float*)d_in[2];
    const float* next_value = (const float*)d_in[3];

    const int B = 8192;
    const int n_elem = B * 256 * 4;          // 8388608
    float* adv = (float*)d_out;
    float* ret = adv + n_elem;

    // Persistent compact front: 512 blocks (2/CU), 2048 waves, each wave
    // loops over 4 sequences at stride 2048 with 2-deep register prefetch.
    gae_scan_kernel<<<512, 256, 0, stream>>>(reward, terminated, value,
                                             next_value, adv, ret);
}

// Round 4
// 175.383 us; speedup vs baseline: 1.1115x; 1.0061x over previous
//
#include <hip/hip_runtime.h>

// GAE: (B=8192, T=256, A=4, 1) fp32.
// g[t] = d[t] + c[t]*g[t+1], c = GAMMA*LMBDA*(1-term), g[T]=0
// adv = g, ret = g + v. d_out = [adv | ret] flat.
//
// Round-7 change (L3-residency theory):
//   HBM BW is pinned at 2.1-2.4 TB/s across ALL structures tried (r1-r3);
//   r3's win came purely from FETCH reduction (L3 hits), not BW. Working
//   set: 134MB inputs + 67MB outputs vs 256MB L3 -> inputs are HALF
//   L3-resident, evicted each iter by the 67MB of output writes allocating
//   through L2/L3. Fix: non-temporal stores (outputs never re-read) so the
//   full input set stays L3-resident; HBM then carries only ~67MB of
//   writes. r2's NT test (WRITE 113MB, regression) was confounded by its
//   +64MB stream-spread bug; this is the clean A/B on the r3 structure.
//
// Structure (r3, verified 63.5us): persistent compact front. 512 blocks
// (2/CU, 8 waves/CU), 2048 waves; wave w handles seqs g*2048+w, g=0..3,
// 2-deep register prefetch overlaps the scan. At any instant the device
// reads a ~8MB contiguous sliding window per array.
//
// Per-wave phases (verified since r1):
//   A: coalesced float4 loads (thread=timestep), compute (d, cont-flag),
//      transpose-write into wave-private LDS slice (swizzled, <=2-way).
//   B: thread (tc,a) owns 16 steps; chunk composite + 4-round shuffle scan
//      + replay. Wave-local s_waitcnt lgkmcnt(0) instead of __syncthreads.
//   C: transpose-read g, coalesced non-temporal float4 stores of adv, ret.

#define GAMMA 0.99f
#define LMBDA 0.95f

typedef float f32x4 __attribute__((ext_vector_type(4)));
typedef unsigned char u8;

constexpr float K0 = GAMMA * LMBDA;

__device__ __forceinline__ void issue_loads(
    const f32x4* __restrict__ R4, const f32x4* __restrict__ T4,
    const f32x4* __restrict__ V4, const f32x4* __restrict__ N4,
    int b, int lane, f32x4 r[4], f32x4 tm[4], f32x4 v[4], f32x4 nv[4])
{
#pragma unroll
    for (int q = 0; q < 4; ++q) {
        const int gi = b * 256 + 64 * q + lane;
        r[q]  = R4[gi];
        tm[q] = T4[gi];
        v[q]  = V4[gi];
        nv[q] = N4[gi];
    }
}

// Consume loaded regs: compute (d, cont-flag), transpose-write into LDS.
__device__ __forceinline__ void phaseA(
    float* __restrict__ D_, u8* __restrict__ C_, int lane,
    const f32x4 r[4], const f32x4 tm[4], const f32x4 nv[4], const f32x4 v[4])
{
#pragma unroll
    for (int q = 0; q < 4; ++q) {
        const int f    = 64 * q + lane;          // float4 index = timestep t
        const int s    = 255 - f;                // scan index (reversed time)
        const int row  = s & 15;
        const int col  = (4 * (s >> 4) + 4 * row) & 63;
        const int addr = row * 64 + col;         // 4-aligned

        f32x4 d4;
        d4.x = r[q].x + GAMMA * nv[q].x * (1.0f - tm[q].x) - v[q].x;
        d4.y = r[q].y + GAMMA * nv[q].y * (1.0f - tm[q].y) - v[q].y;
        d4.z = r[q].z + GAMMA * nv[q].z * (1.0f - tm[q].z) - v[q].z;
        d4.w = r[q].w + GAMMA * nv[q].w * (1.0f - tm[q].w) - v[q].w;
        const unsigned pk = (tm[q].x == 0.0f ? 0x00000001u : 0u)
                          | (tm[q].y == 0.0f ? 0x00000100u : 0u)
                          | (tm[q].z == 0.0f ? 0x00010000u : 0u)
                          | (tm[q].w == 0.0f ? 0x01000000u : 0u);
        *((f32x4*)&D_[addr])    = d4;
        *((unsigned*)&C_[addr]) = pk;
    }
}

// Wave scan over LDS slice + transposed coalesced NT stores.
__device__ __forceinline__ void scan_store(
    float* __restrict__ D_, const u8* __restrict__ C_,
    int lane, int b, const f32x4 v4[4],
    f32x4* __restrict__ adv4, f32x4* __restrict__ ret4)
{
    // Wave-local ordering: phase-A ds_writes complete before phase-B ds_reads.
    asm volatile("s_waitcnt lgkmcnt(0)" ::: "memory");

    const int tc = lane >> 2;    // time chunk 0..15
    const int a  = lane & 3;     // agent channel

    float d[16];
    unsigned mask = 0;           // bit j = continuation flag of step j
#pragma unroll
    for (int j = 0; j < 16; ++j) {
        const int col = (4 * tc + 4 * j + a) & 63;
        d[j] = D_[j * 64 + col];
        mask |= ((unsigned)C_[j * 64 + col]) << j;
    }

    // Local chunk composite: out = D + K * in.
    float D = d[0];
    float K = (mask & 1u) ? K0 : 0.0f;
#pragma unroll
    for (int j = 1; j < 16; ++j) {
        const float cj = ((mask >> j) & 1u) ? K0 : 0.0f;
        D = d[j] + cj * D;
        K = cj * K;
    }

    // Inclusive shuffle scan over tc (lane stride 4): 4 steps.
#pragma unroll
    for (int s2 = 1; s2 < 16; s2 <<= 1) {
        const float pD = __shfl_up(D, (unsigned)(4 * s2), 64);
        const float pK = __shfl_up(K, (unsigned)(4 * s2), 64);
        if (tc >= s2) { D = D + K * pD; K = K * pK; }
    }

    // Exclusive prefix = state entering this chunk.
    float x = __shfl_up(D, 4u, 64);
    if (tc == 0) x = 0.0f;

    // Replay chunk, write g back into D-buffer (d already in regs).
    float g = x;
#pragma unroll
    for (int j = 0; j < 16; ++j) {
        const float cj = ((mask >> j) & 1u) ? K0 : 0.0f;
        g = d[j] + cj * g;
        const int col = (4 * tc + 4 * j + a) & 63;
        D_[j * 64 + col] = g;
    }
    asm volatile("s_waitcnt lgkmcnt(0)" ::: "memory");

    // Transpose-read g, coalesced non-temporal float4 stores: outputs are
    // never re-read; keep them out of L2/L3 so inputs stay resident.
#pragma unroll
    for (int q = 0; q < 4; ++q) {
        const int f   = 64 * q + lane;
        const int s   = 255 - f;
        const int row = s & 15;
        const int col = (4 * (s >> 4) + 4 * row) & 63;
        const f32x4 g4 = *((const f32x4*)&D_[row * 64 + col]);

        const int gi = b * 256 + f;
        __builtin_nontemporal_store(g4, &adv4[gi]);
        const f32x4 rt = g4 + v4[q];
        __builtin_nontemporal_store(rt, &ret4[gi]);
    }
    // Keep the following phase-A ds_writes ordered after this phase's reads.
    asm volatile("" ::: "memory");
}

__global__ __launch_bounds__(256, 2) void gae_scan_kernel(
    const float* __restrict__ reward,
    const float* __restrict__ terminated,
    const float* __restrict__ value,
    const float* __restrict__ next_value,
    float* __restrict__ adv_out,
    float* __restrict__ ret_out)
{
    __shared__ float bufD[4][16 * 64];           // 16 KB: d, then reused for g
    __shared__ u8    bufC[4][16 * 64];           //  4 KB: continuation flags

    const int w    = threadIdx.x >> 6;
    const int lane = threadIdx.x & 63;
    const int wv   = blockIdx.x * 4 + w;         // global wave id, 0..2047

    float* __restrict__ D_ = bufD[w];
    u8*    __restrict__ C_ = bufC[w];

    const f32x4* R4 = (const f32x4*)reward;
    const f32x4* T4 = (const f32x4*)terminated;
    const f32x4* V4 = (const f32x4*)value;
    const f32x4* N4 = (const f32x4*)next_value;
    f32x4* adv4 = (f32x4*)adv_out;
    f32x4* ret4 = (f32x4*)ret_out;

    // Double-buffered register sets for the 2-deep prefetch pipeline.
    f32x4 r[2][4], tm[2][4], v[2][4], nv[2][4];

    issue_loads(R4, T4, V4, N4, wv, lane, r[0], tm[0], v[0], nv[0]);

#pragma unroll
    for (int g = 0; g < 4; ++g) {
        const int cb = g & 1;        // unrolled -> compile-time constant
        const int nb = cb ^ 1;
        const int b  = g * 2048 + wv;

        phaseA(D_, C_, lane, r[cb], tm[cb], nv[cb], v[cb]);

        if (g < 3) {
            // Prefetch next sequence; in flight during the scan below.
            issue_loads(R4, T4, V4, N4, b + 2048, lane,
                        r[nb], tm[nb], v[nb], nv[nb]);
        }

        scan_store(D_, C_, lane, b, v[cb], adv4, ret4);
    }
}

extern "C" void kernel_launch(void* const* d_in, const int* in_sizes, int n_in,
                              void* d_out, int out_size, void* d_ws, size_t ws_size,
                              hipStream_t stream) {
    const float* reward     = (const float*)d_in[0];
    const float* terminated = (const float*)d_in[1];
    const float* value      = (const float*)d_in[2];
    const float* next_value = (const float*)d_in[3];

    const int B = 8192;
    const int n_elem = B * 256 * 4;          // 8388608
    float* adv = (float*)d_out;
    float* ret = adv + n_elem;

    // Persistent compact front: 512 blocks (2/CU), 2048 waves, each wave
    // loops over 4 sequences at stride 2048 with 2-deep register prefetch.
    gae_scan_kernel<<<512, 256, 0, stream>>>(reward, terminated, value,
                                             next_value, adv, ret);
}